// Round 9
// baseline (437.617 us; speedup 1.0000x reference)
//
#include <hip/hip_runtime.h>
#include <hip/hip_bf16.h>
#include <stdint.h>

#define NROWS 16384            // 16*32*32 flattened rows
#define KCODES 8192
#define DIM 256
#define HW 1024                // 32*32
#define CHW (DIM*HW)           // 262144
#define IDX_OFF 4194304        // 16*256*32*32
#define LOSS_OFF 4210688       // IDX_OFF + 16384
#define TAU 1.2e-4f            // candidate margin: grid(3.05e-5) + 2*bf16 tail + safety

typedef unsigned long long u64;
typedef unsigned int u32;
typedef unsigned short ushort_t;

using frag = __attribute__((ext_vector_type(8))) short;   // 8 bf16 (4 VGPRs)
using accf = __attribute__((ext_vector_type(4))) float;   // 4 fp32 acc

__device__ __forceinline__ u32 forder(float f) {
    u32 u = __float_as_uint(f);
    return (u & 0x80000000u) ? ~u : (u | 0x80000000u);
}
__device__ __forceinline__ float unforder(u32 v) {
    u32 u = (v & 0x80000000u) ? (v ^ 0x80000000u) : ~v;
    return __uint_as_float(u);
}
__device__ __forceinline__ ushort_t bf16bits(float v) {
    __hip_bfloat16 t = __float2bfloat16(v);   // RNE
    return *reinterpret_cast<ushort_t*>(&t);
}

// ws layout (bytes):
//   keys   u64[16384]          @ 0        (131072)
//   rn     f32[16384]          @ 131072   (65536)
//   rowmin u32[16384]          @ 196608   (65536)
//   A_bf   u16[16384*256]      @ 262144   (8388608)   hs rows, bf16, [row][k]
//   B_bf   u16[8192*256]       @ 8650752  (4194304)   codebook bf16
//   sbmin  f32[16384*256]      @ 12845056 (16777216)  per (row, 32-code sub) approx min

// hs -> bf16 rows + exact numpy-pairwise rn + rowmin/loss init.
// 256 blocks x 64 threads (full GPU); per-row serial chain UNCHANGED
// (bit-exact vs all passing rounds). Abf writes staged through LDS so each
// wave stores 4 contiguous 256B segments instead of 64 scattered 16B.
__global__ __launch_bounds__(64)
void convert_hs(const float* __restrict__ hs, ushort_t* __restrict__ Abf,
                float* __restrict__ rn, u32* __restrict__ rowmin,
                float* __restrict__ out) {
    __shared__ uint4 tile[64 * 17];   // stride 17: uniform bank coverage
    const int t = threadIdx.x;
    const int row = blockIdx.x * 64 + t;
    rowmin[row] = 0xFFFFFFFFu;
    if (row == 0) out[LOSS_OFF] = 0.0f;
    const int b = row >> 10, hw = row & 1023;
    const float* p = hs + (size_t)b * CHW + hw;
    float halfsum[2];
    #pragma unroll
    for (int h = 0; h < 2; ++h) {
        float r[8];
        for (int i = 0; i < 128; i += 8) {
            ushort_t pk[8];
            #pragma unroll
            for (int j = 0; j < 8; ++j) {
                int c = h * 128 + i + j;
                float v = p[(size_t)c * HW];       // coalesced across lanes
                pk[j] = bf16bits(v);
                float sq = __fmul_rn(v, v);
                r[j] = (i == 0) ? sq : __fadd_rn(r[j], sq);
            }
            uint4 o;
            o.x = (u32)pk[0] | ((u32)pk[1] << 16);
            o.y = (u32)pk[2] | ((u32)pk[3] << 16);
            o.z = (u32)pk[4] | ((u32)pk[5] << 16);
            o.w = (u32)pk[6] | ((u32)pk[7] << 16);
            tile[t * 17 + (i >> 3)] = o;
        }
        halfsum[h] = __fadd_rn(__fadd_rn(__fadd_rn(r[0], r[1]), __fadd_rn(r[2], r[3])),
                               __fadd_rn(__fadd_rn(r[4], r[5]), __fadd_rn(r[6], r[7])));
        __syncthreads();
        #pragma unroll
        for (int pass = 0; pass < 16; ++pass) {
            int rr = pass * 4 + (t >> 4);
            int u  = t & 15;
            uint4 v = tile[rr * 17 + u];
            *reinterpret_cast<uint4*>(
                &Abf[(size_t)(blockIdx.x * 64 + rr) * 256 + h * 128 + u * 8]) = v;
        }
        __syncthreads();
    }
    rn[row] = __fadd_rn(halfsum[0], halfsum[1]);
}

__global__ __launch_bounds__(256)
void convert_cb(const float* __restrict__ cb, ushort_t* __restrict__ Bbf) {
    int i = blockIdx.x * 256 + threadIdx.x;        // float4 index
    float4 v = reinterpret_cast<const float4*>(cb)[i];
    ushort_t pk[4] = {bf16bits(v.x), bf16bits(v.y), bf16bits(v.z), bf16bits(v.w)};
    uint2 o;
    o.x = (u32)pk[0] | ((u32)pk[1] << 16);
    o.y = (u32)pk[2] | ((u32)pk[3] << 16);
    *reinterpret_cast<uint2*>(&Bbf[(size_t)i * 4]) = o;
}

// Approx GEMM: 256 rows x 128 codes per block, wave w owns rows [64w,64w+64).
// XOR-swizzled unpadded LDS (uint4 slot u stored at u^(row&7)): frag reads
// 2-way (free), stores uniform over all 32 banks; LDS 48KB -> 3 blocks/CU
// via __launch_bounds__(256,3).
// 16x16x32 bf16 MFMA, layouts identical to round-6..8-verified:
//   A/B frag: [m|n = lane&15][k = (lane>>4)*8 + j]
//   C/D:      col = lane&15, row-in-tile = (lane>>4)*4 + reg
__global__ __launch_bounds__(256, 3)
void mfma_approx(const ushort_t* __restrict__ Abf, const ushort_t* __restrict__ Bbf,
                 float* __restrict__ sbmin, u32* __restrict__ rowmin) {
    __shared__ uint4 As4[256 * 8];   // [row][u^(row&7)] : 32 KB
    __shared__ uint4 Bs4[128 * 8];   // [code][u^(code&7)] : 16 KB

    const int tid = threadIdx.x;
    const int n0 = blockIdx.x << 8;     // 256 rows per block
    const int c0 = blockIdx.y << 7;     // 128 codes per block
    const int w = tid >> 6, L = tid & 63;
    const int m = L & 15, q = L >> 4;
    const int bsrow = tid >> 1, bshalf = tid & 1;   // B staging: 2 thr/code

    accf acc[4][8];
    #pragma unroll
    for (int rt = 0; rt < 4; ++rt)
        #pragma unroll
        for (int ct = 0; ct < 8; ++ct) acc[rt][ct] = (accf){0.f, 0.f, 0.f, 0.f};

    for (int kc = 0; kc < DIM; kc += 64) {
        // A: thread t stages row n0+t's 64-k slice (8 uint4), swizzled
        const uint4* ga = reinterpret_cast<const uint4*>(&Abf[(size_t)(n0 + tid) * 256 + kc]);
        #pragma unroll
        for (int j = 0; j < 8; ++j) As4[tid * 8 + (j ^ (tid & 7))] = ga[j];
        // B: 2 threads per code row, 4 uint4 each, swizzled
        const uint4* gb = reinterpret_cast<const uint4*>(&Bbf[(size_t)(c0 + bsrow) * 256 + kc]);
        #pragma unroll
        for (int j = 0; j < 4; ++j) {
            int u = bshalf * 4 + j;
            Bs4[bsrow * 8 + (u ^ (bsrow & 7))] = gb[u];
        }
        __syncthreads();
        #pragma unroll
        for (int ks = 0; ks < 2; ++ks) {
            const int u = ks * 4 + q;
            const int us = u ^ (m & 7);
            frag a[4];
            #pragma unroll
            for (int rt = 0; rt < 4; ++rt)
                a[rt] = *reinterpret_cast<const frag*>(&As4[(64 * w + 16 * rt + m) * 8 + us]);
            #pragma unroll
            for (int ct = 0; ct < 8; ++ct) {
                frag bfr = *reinterpret_cast<const frag*>(&Bs4[(16 * ct + m) * 8 + us]);
                #pragma unroll
                for (int rt = 0; rt < 4; ++rt)
                    acc[rt][ct] = __builtin_amdgcn_mfma_f32_16x16x32_bf16(a[rt], bfr, acc[rt][ct], 0, 0, 0);
            }
        }
        __syncthreads();
    }

    // epilogue: subblock (32-code) mins + row min (unchanged)
    #pragma unroll
    for (int rt = 0; rt < 4; ++rt) {
        #pragma unroll
        for (int reg = 0; reg < 4; ++reg) {
            float mn[4];
            #pragma unroll
            for (int p = 0; p < 4; ++p) {
                float s0 = -2.0f * acc[rt][2 * p][reg];
                float s1 = -2.0f * acc[rt][2 * p + 1][reg];
                mn[p] = fminf(s0, s1);
            }
            #pragma unroll
            for (int sh = 1; sh < 16; sh <<= 1) {
                #pragma unroll
                for (int p = 0; p < 4; ++p)
                    mn[p] = fminf(mn[p], __shfl_xor(mn[p], sh, 64));
            }
            if (m == 0) {   // lanes 0,16,32,48 (one per quad)
                int row = n0 + 64 * w + 16 * rt + 4 * q + reg;
                #pragma unroll
                for (int p = 0; p < 4; ++p)
                    sbmin[(size_t)row * 256 + (blockIdx.y << 2) + p] = mn[p];
                float m4 = fminf(fminf(mn[0], mn[1]), fminf(mn[2], mn[3]));
                atomicMin(&rowmin[row], forder(m4));
            }
        }
    }
}

// Exact rescore (unchanged semantics): qualifying subblocks rescored with the
// EXACT chain (sequential k fp32 fmaf, fl32(rn-2*dot)); ties -> lowest index.
__global__ __launch_bounds__(64)
void rescore(const float* __restrict__ hs, const float* __restrict__ cb,
             const float* __restrict__ rn, const float* __restrict__ sbmin,
             const u32* __restrict__ rowmin, u64* __restrict__ keys) {
    __shared__ float fs[256];
    __shared__ int list[256];
    __shared__ int cnt;
    const int row = blockIdx.x;
    const int l = threadIdx.x;
    if (l == 0) cnt = 0;
    const int b = row >> 10, hw = row & 1023;
    const float* hp = hs + (size_t)b * CHW + hw;
    #pragma unroll
    for (int j = 0; j < 4; ++j) fs[l + 64 * j] = hp[(size_t)(l + 64 * j) * HW];
    __syncthreads();

    float thr = unforder(rowmin[row]) + TAU;
    #pragma unroll
    for (int j = 0; j < 4; ++j) {
        int sb = l + 64 * j;
        if (sbmin[(size_t)row * 256 + sb] <= thr) {
            int pos = atomicAdd(&cnt, 1);
            list[pos] = sb;
        }
    }
    __syncthreads();
    const int C = cnt;
    const float rn_row = rn[row];
    u64 best = ~0ull;
    for (int it = 0; it < C; it += 2) {
        int slot = it + (l >> 5);
        if (slot < C) {
            int code = list[slot] * 32 + (l & 31);
            const float4* e4 = reinterpret_cast<const float4*>(&cb[(size_t)code << 8]);
            float acc = 0.0f;
            #pragma unroll 16
            for (int kk = 0; kk < 64; ++kk) {
                float4 ev = e4[kk];
                float4 fv = *reinterpret_cast<const float4*>(&fs[kk << 2]);
                acc = fmaf(fv.x, ev.x, acc);
                acc = fmaf(fv.y, ev.y, acc);
                acc = fmaf(fv.z, ev.z, acc);
                acc = fmaf(fv.w, ev.w, acc);
            }
            float s = __fadd_rn(rn_row, -2.0f * acc);
            u64 key = ((u64)forder(s) << 32) | (u64)code;
            if (key < best) best = key;
        }
    }
    #pragma unroll
    for (int sh = 1; sh < 64; sh <<= 1) {
        u64 o = __shfl_xor(best, sh, 64);
        if (o < best) best = o;
    }
    if (l == 0) keys[row] = best;
}

// Gather v2: 512 blocks, each owns (b, 32-hw chunk) x all 256 c.
// cb rows read COALESCED once into LDS (16 MB total vs ~270 MB scattered),
// outputs written coalesced. Values identical: q gathered fp32, x+(q-x).
__global__ __launch_bounds__(256)
void gather_kernel(const float* __restrict__ hs, const float* __restrict__ cb,
                   const u64* __restrict__ keys, float* __restrict__ out) {
    __shared__ int codes_s[32];
    __shared__ float q_s[32][257];
    __shared__ float red[4];
    const int g = blockIdx.x;
    const int b = g >> 5;
    const int hw0 = (g & 31) << 5;
    const int t = threadIdx.x;
    const int nbase = b * HW + hw0;

    if (t < 32) {
        int code = (int)(keys[nbase + t] & 0xFFFFFFFFULL);
        codes_s[t] = code;
        out[IDX_OFF + nbase + t] = (float)code;
    }
    __syncthreads();

    // stage 32 cb rows coalesced: thread (r = t>>3, f4 = t&7) loads 8 float4
    const int r = t >> 3, f4 = t & 7;
    const float4* crow = reinterpret_cast<const float4*>(cb + (size_t)codes_s[r] * DIM);
    #pragma unroll
    for (int j = 0; j < 8; ++j) {
        float4 v = crow[f4 + 8 * j];
        *reinterpret_cast<float4*>(&q_s[r][4 * (f4 + 8 * j)]) = v;
    }
    __syncthreads();

    float d2 = 0.0f;
    const int hw = t & 31, cof = t >> 5;   // 8 c-lanes
    #pragma unroll 8
    for (int it = 0; it < 32; ++it) {
        int c = it * 8 + cof;
        size_t off = (size_t)b * CHW + (size_t)c * HW + hw0 + hw;
        float x = hs[off];
        float qv = q_s[hw][c];
        out[off] = x + (qv - x);           // straight-through forward, exact formula
        float d = qv - x;
        d2 = fmaf(d, d, d2);
    }
    #pragma unroll
    for (int sh = 32; sh >= 1; sh >>= 1) d2 += __shfl_xor(d2, sh, 64);
    if ((t & 63) == 0) red[t >> 6] = d2;
    __syncthreads();
    if (t == 0) {
        float tot = red[0] + red[1] + red[2] + red[3];
        atomicAdd(out + LOSS_OFF, tot * (1.25f / 4194304.0f));  // (1+0.25)*mean
    }
}

extern "C" void kernel_launch(void* const* d_in, const int* in_sizes, int n_in,
                              void* d_out, int out_size, void* d_ws, size_t ws_size,
                              hipStream_t stream) {
    const float* hs = (const float*)d_in[0];   // (16,256,32,32) f32
    const float* cb = (const float*)d_in[1];   // (8192,256) f32
    float* out = (float*)d_out;
    char* ws = (char*)d_ws;
    u64*      keys   = (u64*)(ws + 0);
    float*    rn     = (float*)(ws + 131072);
    u32*      rowmin = (u32*)(ws + 196608);
    ushort_t* Abf    = (ushort_t*)(ws + 262144);
    ushort_t* Bbf    = (ushort_t*)(ws + 8650752);
    float*    sbmin  = (float*)(ws + 12845056);

    convert_hs<<<NROWS / 64, 64, 0, stream>>>(hs, Abf, rn, rowmin, out);
    convert_cb<<<(KCODES * DIM / 4) / 256, 256, 0, stream>>>(cb, Bbf);
    mfma_approx<<<dim3(NROWS / 256, KCODES / 128), 256, 0, stream>>>(Abf, Bbf, sbmin, rowmin);
    rescore<<<NROWS, 64, 0, stream>>>(hs, cb, rn, sbmin, rowmin, keys);
    gather_kernel<<<512, 256, 0, stream>>>(hs, cb, keys, out);
}

// Round 10
// 320.286 us; speedup vs baseline: 1.3663x; 1.3663x over previous
//
#include <hip/hip_runtime.h>
#include <hip/hip_bf16.h>
#include <stdint.h>

#define NROWS 16384            // 16*32*32 flattened rows
#define KCODES 8192
#define DIM 256
#define HW 1024                // 32*32
#define CHW (DIM*HW)           // 262144
#define IDX_OFF 4194304        // 16*256*32*32
#define LOSS_OFF 4210688       // IDX_OFF + 16384
#define TAU 1.2e-4f            // candidate margin: grid(3.05e-5) + 2*bf16 tail + safety

typedef unsigned long long u64;
typedef unsigned int u32;
typedef unsigned short ushort_t;

using frag = __attribute__((ext_vector_type(8))) short;   // 8 bf16 (4 VGPRs)
using accf = __attribute__((ext_vector_type(4))) float;   // 4 fp32 acc

__device__ __forceinline__ u32 forder(float f) {
    u32 u = __float_as_uint(f);
    return (u & 0x80000000u) ? ~u : (u | 0x80000000u);
}
__device__ __forceinline__ float unforder(u32 v) {
    u32 u = (v & 0x80000000u) ? (v ^ 0x80000000u) : ~v;
    return __uint_as_float(u);
}
__device__ __forceinline__ ushort_t bf16bits(float v) {
    __hip_bfloat16 t = __float2bfloat16(v);   // RNE
    return *reinterpret_cast<ushort_t*>(&t);
}
__device__ __forceinline__ void async_cp16(const uint4* gp, uint4* lp) {
    __builtin_amdgcn_global_load_lds(
        (const __attribute__((address_space(1))) unsigned int*)gp,
        (__attribute__((address_space(3))) unsigned int*)lp, 16, 0, 0);
}

// ws layout (bytes):
//   keys   u64[16384]          @ 0        (131072)
//   rn     f32[16384]          @ 131072   (65536)
//   rowmin u32[16384]          @ 196608   (65536)
//   A_bf   u16[16384*256]      @ 262144   (8388608)  PLANE-MAJOR+SWIZZLED:
//          uint4 idx = g*131072 + row*8 + ((u&7)^(row&7)), g=k-group(64k), u=k/8
//   B_bf   u16[8192*256]       @ 8650752  (4194304)  uint4 idx = g*65536 + code*8 + slot
//   sbmin  f32[16384*256]      @ 12845056 (16777216) per (row, 32-code sub) approx min

// hs -> bf16 rows (plane-major swizzled) + exact numpy-pairwise rn + inits.
// Per-row serial chain UNCHANGED (bit-exact vs all passing rounds).
__global__ __launch_bounds__(64)
void convert_hs(const float* __restrict__ hs, ushort_t* __restrict__ Abf,
                float* __restrict__ rn, u32* __restrict__ rowmin,
                float* __restrict__ out) {
    __shared__ uint4 tile[64 * 17];   // stride 17: uniform bank coverage
    const int t = threadIdx.x;
    const int row0 = blockIdx.x * 64;
    const int row = row0 + t;
    rowmin[row] = 0xFFFFFFFFu;
    if (row == 0) out[LOSS_OFF] = 0.0f;
    const int b = row >> 10, hw = row & 1023;
    const float* p = hs + (size_t)b * CHW + hw;
    uint4* Abf4 = reinterpret_cast<uint4*>(Abf);
    float halfsum[2];
    #pragma unroll
    for (int h = 0; h < 2; ++h) {
        float r[8];
        for (int i = 0; i < 128; i += 8) {
            ushort_t pk[8];
            #pragma unroll
            for (int j = 0; j < 8; ++j) {
                int c = h * 128 + i + j;
                float v = p[(size_t)c * HW];       // coalesced across lanes
                pk[j] = bf16bits(v);
                float sq = __fmul_rn(v, v);
                r[j] = (i == 0) ? sq : __fadd_rn(r[j], sq);
            }
            uint4 o;
            o.x = (u32)pk[0] | ((u32)pk[1] << 16);
            o.y = (u32)pk[2] | ((u32)pk[3] << 16);
            o.z = (u32)pk[4] | ((u32)pk[5] << 16);
            o.w = (u32)pk[6] | ((u32)pk[7] << 16);
            tile[t * 17 + (i >> 3)] = o;
        }
        halfsum[h] = __fadd_rn(__fadd_rn(__fadd_rn(r[0], r[1]), __fadd_rn(r[2], r[3])),
                               __fadd_rn(__fadd_rn(r[4], r[5]), __fadd_rn(r[6], r[7])));
        __syncthreads();
        #pragma unroll
        for (int pass = 0; pass < 16; ++pass) {
            int rr = pass * 4 + (t >> 4);
            int uh = t & 15;
            uint4 v = tile[rr * 17 + uh];
            int orow = row0 + rr;
            int u = h * 16 + uh;                  // global uint4 k-slot 0..31
            int g = u >> 3;
            int slot = (u & 7) ^ (orow & 7);
            Abf4[(size_t)g * 131072 + (size_t)orow * 8 + slot] = v;
        }
        __syncthreads();
    }
    rn[row] = __fadd_rn(halfsum[0], halfsum[1]);
}

// codebook -> bf16, plane-major swizzled. One thread per output uint4 (coalesced).
__global__ __launch_bounds__(256)
void convert_cb(const float* __restrict__ cb, ushort_t* __restrict__ Bbf) {
    int o = blockIdx.x * 256 + threadIdx.x;        // output uint4 idx, 262144 total
    int g = o >> 16;                               // 65536 uint4 per plane
    int rem = o & 65535;
    int code = rem >> 3;
    int slot = rem & 7;
    int u = slot ^ (code & 7);                     // source uint4-in-group
    const float4* src = reinterpret_cast<const float4*>(
        cb + (size_t)code * DIM + (size_t)(g * 8 + u) * 8);
    float4 v0 = src[0], v1 = src[1];
    uint4 out_v;
    out_v.x = (u32)bf16bits(v0.x) | ((u32)bf16bits(v0.y) << 16);
    out_v.y = (u32)bf16bits(v0.z) | ((u32)bf16bits(v0.w) << 16);
    out_v.z = (u32)bf16bits(v1.x) | ((u32)bf16bits(v1.y) << 16);
    out_v.w = (u32)bf16bits(v1.z) | ((u32)bf16bits(v1.w) << 16);
    reinterpret_cast<uint4*>(Bbf)[o] = out_v;
}

// Approx GEMM: 256 rows x 128 codes per block, wave w owns rows [64w,64w+64).
// Staging via global_load_lds width-16 (async DMA, no VGPR round-trip): the
// pre-swizzled plane-major Abf/Bbf layouts make the global side perfectly
// linear per wave (1KB contiguous per instr) while LDS lands in the
// round-9-verified conflict-free xor-swizzled layout.
// 16x16x32 bf16 MFMA, layouts identical to round-6..9-verified:
//   A/B frag: [m|n = lane&15][k = (lane>>4)*8 + j], uint4 slot u^(m&7)
//   C/D:      col = lane&15, row-in-tile = (lane>>4)*4 + reg
__global__ __launch_bounds__(256, 2)
void mfma_approx(const ushort_t* __restrict__ Abf, const ushort_t* __restrict__ Bbf,
                 float* __restrict__ sbmin, u32* __restrict__ rowmin) {
    __shared__ uint4 As4[2048];   // 32 KB: [row][slot]
    __shared__ uint4 Bs4[1024];   // 16 KB: [code][slot]

    const int tid = threadIdx.x;
    const int n0 = blockIdx.x << 8;     // 256 rows per block
    const int c0 = blockIdx.y << 7;     // 128 codes per block
    const int w = tid >> 6, L = tid & 63;
    const int m = L & 15, q = L >> 4;
    const uint4* gA = reinterpret_cast<const uint4*>(Abf);
    const uint4* gB = reinterpret_cast<const uint4*>(Bbf);

    accf acc[4][8];
    #pragma unroll
    for (int rt = 0; rt < 4; ++rt)
        #pragma unroll
        for (int ct = 0; ct < 8; ++ct) acc[rt][ct] = (accf){0.f, 0.f, 0.f, 0.f};

    for (int g = 0; g < 4; ++g) {       // kc = 64*g
        // A: 8 async 1KB copies per wave (linear global, linear LDS)
        #pragma unroll
        for (int t = 0; t < 8; ++t) {
            int j0 = (w << 9) + (t << 6) + L;
            async_cp16(gA + ((size_t)g * 131072 + (size_t)n0 * 8 + j0),
                       &As4[(w << 9) + (t << 6)]);
        }
        // B: 4 async 1KB copies per wave
        #pragma unroll
        for (int t = 0; t < 4; ++t) {
            int j0 = (w << 8) + (t << 6) + L;
            async_cp16(gB + ((size_t)g * 65536 + (size_t)c0 * 8 + j0),
                       &Bs4[(w << 8) + (t << 6)]);
        }
        __syncthreads();               // drains vmcnt (async copies) + barrier
        #pragma unroll
        for (int ks = 0; ks < 2; ++ks) {
            const int us = (ks * 4 + q) ^ (m & 7);
            frag a[4];
            #pragma unroll
            for (int rt = 0; rt < 4; ++rt)
                a[rt] = *reinterpret_cast<const frag*>(&As4[(64 * w + 16 * rt + m) * 8 + us]);
            #pragma unroll
            for (int ct = 0; ct < 8; ++ct) {
                frag bfr = *reinterpret_cast<const frag*>(&Bs4[(16 * ct + m) * 8 + us]);
                #pragma unroll
                for (int rt = 0; rt < 4; ++rt)
                    acc[rt][ct] = __builtin_amdgcn_mfma_f32_16x16x32_bf16(a[rt], bfr, acc[rt][ct], 0, 0, 0);
            }
        }
        __syncthreads();
    }

    // epilogue: subblock (32-code) mins + row min (unchanged, verified r6-r9)
    #pragma unroll
    for (int rt = 0; rt < 4; ++rt) {
        #pragma unroll
        for (int reg = 0; reg < 4; ++reg) {
            float mn[4];
            #pragma unroll
            for (int p = 0; p < 4; ++p) {
                float s0 = -2.0f * acc[rt][2 * p][reg];
                float s1 = -2.0f * acc[rt][2 * p + 1][reg];
                mn[p] = fminf(s0, s1);
            }
            #pragma unroll
            for (int sh = 1; sh < 16; sh <<= 1) {
                #pragma unroll
                for (int p = 0; p < 4; ++p)
                    mn[p] = fminf(mn[p], __shfl_xor(mn[p], sh, 64));
            }
            if (m == 0) {   // lanes 0,16,32,48 (one per quad)
                int row = n0 + 64 * w + 16 * rt + 4 * q + reg;
                #pragma unroll
                for (int p = 0; p < 4; ++p)
                    sbmin[(size_t)row * 256 + (blockIdx.y << 2) + p] = mn[p];
                float m4 = fminf(fminf(mn[0], mn[1]), fminf(mn[2], mn[3]));
                atomicMin(&rowmin[row], forder(m4));
            }
        }
    }
}

// Exact rescore (unchanged semantics): qualifying subblocks rescored with the
// EXACT chain (sequential k fp32 fmaf, fl32(rn-2*dot)); ties -> lowest index.
__global__ __launch_bounds__(64)
void rescore(const float* __restrict__ hs, const float* __restrict__ cb,
             const float* __restrict__ rn, const float* __restrict__ sbmin,
             const u32* __restrict__ rowmin, u64* __restrict__ keys) {
    __shared__ float fs[256];
    __shared__ int list[256];
    __shared__ int cnt;
    const int row = blockIdx.x;
    const int l = threadIdx.x;
    if (l == 0) cnt = 0;
    const int b = row >> 10, hw = row & 1023;
    const float* hp = hs + (size_t)b * CHW + hw;
    #pragma unroll
    for (int j = 0; j < 4; ++j) fs[l + 64 * j] = hp[(size_t)(l + 64 * j) * HW];
    __syncthreads();

    float thr = unforder(rowmin[row]) + TAU;
    #pragma unroll
    for (int j = 0; j < 4; ++j) {
        int sb = l + 64 * j;
        if (sbmin[(size_t)row * 256 + sb] <= thr) {
            int pos = atomicAdd(&cnt, 1);
            list[pos] = sb;
        }
    }
    __syncthreads();
    const int C = cnt;
    const float rn_row = rn[row];
    u64 best = ~0ull;
    for (int it = 0; it < C; it += 2) {
        int slot = it + (l >> 5);
        if (slot < C) {
            int code = list[slot] * 32 + (l & 31);
            const float4* e4 = reinterpret_cast<const float4*>(&cb[(size_t)code << 8]);
            float acc = 0.0f;
            #pragma unroll 16
            for (int kk = 0; kk < 64; ++kk) {
                float4 ev = e4[kk];
                float4 fv = *reinterpret_cast<const float4*>(&fs[kk << 2]);
                acc = fmaf(fv.x, ev.x, acc);
                acc = fmaf(fv.y, ev.y, acc);
                acc = fmaf(fv.z, ev.z, acc);
                acc = fmaf(fv.w, ev.w, acc);
            }
            float s = __fadd_rn(rn_row, -2.0f * acc);
            u64 key = ((u64)forder(s) << 32) | (u64)code;
            if (key < best) best = key;
        }
    }
    #pragma unroll
    for (int sh = 1; sh < 64; sh <<= 1) {
        u64 o = __shfl_xor(best, sh, 64);
        if (o < best) best = o;
    }
    if (l == 0) keys[row] = best;
}

// Gather: 512 blocks, each owns (b, 32-hw chunk) x all 256 c. cb rows read
// coalesced once into LDS; outputs coalesced. Values exact: x + (q - x).
__global__ __launch_bounds__(256)
void gather_kernel(const float* __restrict__ hs, const float* __restrict__ cb,
                   const u64* __restrict__ keys, float* __restrict__ out) {
    __shared__ int codes_s[32];
    __shared__ float q_s[32][257];
    __shared__ float red[4];
    const int g = blockIdx.x;
    const int b = g >> 5;
    const int hw0 = (g & 31) << 5;
    const int t = threadIdx.x;
    const int nbase = b * HW + hw0;

    if (t < 32) {
        int code = (int)(keys[nbase + t] & 0xFFFFFFFFULL);
        codes_s[t] = code;
        out[IDX_OFF + nbase + t] = (float)code;
    }
    __syncthreads();

    const int r = t >> 3, f4 = t & 7;
    const float4* crow = reinterpret_cast<const float4*>(cb + (size_t)codes_s[r] * DIM);
    #pragma unroll
    for (int j = 0; j < 8; ++j) {
        float4 v = crow[f4 + 8 * j];
        *reinterpret_cast<float4*>(&q_s[r][4 * (f4 + 8 * j)]) = v;
    }
    __syncthreads();

    float d2 = 0.0f;
    const int hw = t & 31, cof = t >> 5;   // 8 c-lanes
    #pragma unroll 8
    for (int it = 0; it < 32; ++it) {
        int c = it * 8 + cof;
        size_t off = (size_t)b * CHW + (size_t)c * HW + hw0 + hw;
        float x = hs[off];
        float qv = q_s[hw][c];
        out[off] = x + (qv - x);           // straight-through forward, exact formula
        float d = qv - x;
        d2 = fmaf(d, d, d2);
    }
    #pragma unroll
    for (int sh = 32; sh >= 1; sh >>= 1) d2 += __shfl_xor(d2, sh, 64);
    if ((t & 63) == 0) red[t >> 6] = d2;
    __syncthreads();
    if (t == 0) {
        float tot = red[0] + red[1] + red[2] + red[3];
        atomicAdd(out + LOSS_OFF, tot * (1.25f / 4194304.0f));  // (1+0.25)*mean
    }
}

extern "C" void kernel_launch(void* const* d_in, const int* in_sizes, int n_in,
                              void* d_out, int out_size, void* d_ws, size_t ws_size,
                              hipStream_t stream) {
    const float* hs = (const float*)d_in[0];   // (16,256,32,32) f32
    const float* cb = (const float*)d_in[1];   // (8192,256) f32
    float* out = (float*)d_out;
    char* ws = (char*)d_ws;
    u64*      keys   = (u64*)(ws + 0);
    float*    rn     = (float*)(ws + 131072);
    u32*      rowmin = (u32*)(ws + 196608);
    ushort_t* Abf    = (ushort_t*)(ws + 262144);
    ushort_t* Bbf    = (ushort_t*)(ws + 8650752);
    float*    sbmin  = (float*)(ws + 12845056);

    convert_hs<<<NROWS / 64, 64, 0, stream>>>(hs, Abf, rn, rowmin, out);
    convert_cb<<<1024, 256, 0, stream>>>(cb, Bbf);
    mfma_approx<<<dim3(NROWS / 256, KCODES / 128), 256, 0, stream>>>(Abf, Bbf, sbmin, rowmin);
    rescore<<<NROWS, 64, 0, stream>>>(hs, cb, rn, sbmin, rowmin, keys);
    gather_kernel<<<512, 256, 0, stream>>>(hs, cb, keys, out);
}

// Round 11
// 313.251 us; speedup vs baseline: 1.3970x; 1.0225x over previous
//
#include <hip/hip_runtime.h>
#include <hip/hip_bf16.h>
#include <stdint.h>

#define NROWS 16384            // 16*32*32 flattened rows
#define KCODES 8192
#define DIM 256
#define HW 1024                // 32*32
#define CHW (DIM*HW)           // 262144
#define IDX_OFF 4194304        // 16*256*32*32
#define LOSS_OFF 4210688       // IDX_OFF + 16384
#define TAU 1.2e-4f            // candidate margin: grid(3.05e-5) + 2*bf16 tail + safety

typedef unsigned long long u64;
typedef unsigned int u32;
typedef unsigned short ushort_t;

using frag = __attribute__((ext_vector_type(8))) short;   // 8 bf16 (4 VGPRs)
using accf = __attribute__((ext_vector_type(4))) float;   // 4 fp32 acc

__device__ __forceinline__ u32 forder(float f) {
    u32 u = __float_as_uint(f);
    return (u & 0x80000000u) ? ~u : (u | 0x80000000u);
}
__device__ __forceinline__ float unforder(u32 v) {
    u32 u = (v & 0x80000000u) ? (v ^ 0x80000000u) : ~v;
    return __uint_as_float(u);
}
__device__ __forceinline__ ushort_t bf16bits(float v) {
    __hip_bfloat16 t = __float2bfloat16(v);   // RNE
    return *reinterpret_cast<ushort_t*>(&t);
}
__device__ __forceinline__ void async_cp16(const uint4* gp, uint4* lp) {
    __builtin_amdgcn_global_load_lds(
        (const __attribute__((address_space(1))) unsigned int*)gp,
        (__attribute__((address_space(3))) unsigned int*)lp, 16, 0, 0);
}

// ws layout (bytes):
//   keys   u64[16384]          @ 0        (131072)
//   rn     f32[16384]          @ 131072   (65536)
//   rowmin u32[16384]          @ 196608   (65536)
//   A_bf   u16[16384*256]      @ 262144   (8388608)  PLANE-MAJOR+SWIZZLED:
//          uint4 idx = g*131072 + row*8 + ((u&7)^(row&7)), g=k-group(64k), u=k/8
//   B_bf   u16[8192*256]       @ 8650752  (4194304)  uint4 idx = g*65536 + code*8 + slot
//   sbmin  f32[16384*256]      @ 12845056 (16777216) per (row, 32-code sub) approx min

// hs -> bf16 rows (plane-major swizzled) + exact numpy-pairwise rn + inits.
// Per-row serial chain UNCHANGED (bit-exact vs all passing rounds).
__global__ __launch_bounds__(64)
void convert_hs(const float* __restrict__ hs, ushort_t* __restrict__ Abf,
                float* __restrict__ rn, u32* __restrict__ rowmin,
                float* __restrict__ out) {
    __shared__ uint4 tile[64 * 17];   // stride 17: uniform bank coverage
    const int t = threadIdx.x;
    const int row0 = blockIdx.x * 64;
    const int row = row0 + t;
    rowmin[row] = 0xFFFFFFFFu;
    if (row == 0) out[LOSS_OFF] = 0.0f;
    const int b = row >> 10, hw = row & 1023;
    const float* p = hs + (size_t)b * CHW + hw;
    uint4* Abf4 = reinterpret_cast<uint4*>(Abf);
    float halfsum[2];
    #pragma unroll
    for (int h = 0; h < 2; ++h) {
        float r[8];
        for (int i = 0; i < 128; i += 8) {
            ushort_t pk[8];
            #pragma unroll
            for (int j = 0; j < 8; ++j) {
                int c = h * 128 + i + j;
                float v = p[(size_t)c * HW];       // coalesced across lanes
                pk[j] = bf16bits(v);
                float sq = __fmul_rn(v, v);
                r[j] = (i == 0) ? sq : __fadd_rn(r[j], sq);
            }
            uint4 o;
            o.x = (u32)pk[0] | ((u32)pk[1] << 16);
            o.y = (u32)pk[2] | ((u32)pk[3] << 16);
            o.z = (u32)pk[4] | ((u32)pk[5] << 16);
            o.w = (u32)pk[6] | ((u32)pk[7] << 16);
            tile[t * 17 + (i >> 3)] = o;
        }
        halfsum[h] = __fadd_rn(__fadd_rn(__fadd_rn(r[0], r[1]), __fadd_rn(r[2], r[3])),
                               __fadd_rn(__fadd_rn(r[4], r[5]), __fadd_rn(r[6], r[7])));
        __syncthreads();
        #pragma unroll
        for (int pass = 0; pass < 16; ++pass) {
            int rr = pass * 4 + (t >> 4);
            int uh = t & 15;
            uint4 v = tile[rr * 17 + uh];
            int orow = row0 + rr;
            int u = h * 16 + uh;                  // global uint4 k-slot 0..31
            int g = u >> 3;
            int slot = (u & 7) ^ (orow & 7);
            Abf4[(size_t)g * 131072 + (size_t)orow * 8 + slot] = v;
        }
        __syncthreads();
    }
    rn[row] = __fadd_rn(halfsum[0], halfsum[1]);
}

// codebook -> bf16, plane-major swizzled. One thread per output uint4 (coalesced).
__global__ __launch_bounds__(256)
void convert_cb(const float* __restrict__ cb, ushort_t* __restrict__ Bbf) {
    int o = blockIdx.x * 256 + threadIdx.x;        // output uint4 idx, 262144 total
    int g = o >> 16;                               // 65536 uint4 per plane
    int rem = o & 65535;
    int code = rem >> 3;
    int slot = rem & 7;
    int u = slot ^ (code & 7);                     // source uint4-in-group
    const float4* src = reinterpret_cast<const float4*>(
        cb + (size_t)code * DIM + (size_t)(g * 8 + u) * 8);
    float4 v0 = src[0], v1 = src[1];
    uint4 out_v;
    out_v.x = (u32)bf16bits(v0.x) | ((u32)bf16bits(v0.y) << 16);
    out_v.y = (u32)bf16bits(v0.z) | ((u32)bf16bits(v0.w) << 16);
    out_v.z = (u32)bf16bits(v1.x) | ((u32)bf16bits(v1.y) << 16);
    out_v.w = (u32)bf16bits(v1.z) | ((u32)bf16bits(v1.w) << 16);
    reinterpret_cast<uint4*>(Bbf)[o] = out_v;
}

// Approx GEMM: 256 rows x 128 codes per block, wave w owns rows [64w,64w+64).
// Staging via global_load_lds width-16 (async DMA, no VGPR round-trip); the
// pre-swizzled plane-major Abf/Bbf layouts make the global side linear while
// LDS lands in the round-9-verified conflict-free xor-swizzled layout.
// 16x16x32 bf16 MFMA, layouts identical to round-6..10-verified.
__global__ __launch_bounds__(256, 2)
void mfma_approx(const ushort_t* __restrict__ Abf, const ushort_t* __restrict__ Bbf,
                 float* __restrict__ sbmin, u32* __restrict__ rowmin) {
    __shared__ uint4 As4[2048];   // 32 KB: [row][slot]
    __shared__ uint4 Bs4[1024];   // 16 KB: [code][slot]

    const int tid = threadIdx.x;
    const int n0 = blockIdx.x << 8;     // 256 rows per block
    const int c0 = blockIdx.y << 7;     // 128 codes per block
    const int w = tid >> 6, L = tid & 63;
    const int m = L & 15, q = L >> 4;
    const uint4* gA = reinterpret_cast<const uint4*>(Abf);
    const uint4* gB = reinterpret_cast<const uint4*>(Bbf);

    accf acc[4][8];
    #pragma unroll
    for (int rt = 0; rt < 4; ++rt)
        #pragma unroll
        for (int ct = 0; ct < 8; ++ct) acc[rt][ct] = (accf){0.f, 0.f, 0.f, 0.f};

    for (int g = 0; g < 4; ++g) {       // kc = 64*g
        #pragma unroll
        for (int t = 0; t < 8; ++t) {
            int j0 = (w << 9) + (t << 6) + L;
            async_cp16(gA + ((size_t)g * 131072 + (size_t)n0 * 8 + j0),
                       &As4[(w << 9) + (t << 6)]);
        }
        #pragma unroll
        for (int t = 0; t < 4; ++t) {
            int j0 = (w << 8) + (t << 6) + L;
            async_cp16(gB + ((size_t)g * 65536 + (size_t)c0 * 8 + j0),
                       &Bs4[(w << 8) + (t << 6)]);
        }
        __syncthreads();               // drains vmcnt (async copies) + barrier
        #pragma unroll
        for (int ks = 0; ks < 2; ++ks) {
            const int us = (ks * 4 + q) ^ (m & 7);
            frag a[4];
            #pragma unroll
            for (int rt = 0; rt < 4; ++rt)
                a[rt] = *reinterpret_cast<const frag*>(&As4[(64 * w + 16 * rt + m) * 8 + us]);
            #pragma unroll
            for (int ct = 0; ct < 8; ++ct) {
                frag bfr = *reinterpret_cast<const frag*>(&Bs4[(16 * ct + m) * 8 + us]);
                #pragma unroll
                for (int rt = 0; rt < 4; ++rt)
                    acc[rt][ct] = __builtin_amdgcn_mfma_f32_16x16x32_bf16(a[rt], bfr, acc[rt][ct], 0, 0, 0);
            }
        }
        __syncthreads();
    }

    // epilogue: subblock (32-code) mins + row min (unchanged, verified r6-r10)
    #pragma unroll
    for (int rt = 0; rt < 4; ++rt) {
        #pragma unroll
        for (int reg = 0; reg < 4; ++reg) {
            float mn[4];
            #pragma unroll
            for (int p = 0; p < 4; ++p) {
                float s0 = -2.0f * acc[rt][2 * p][reg];
                float s1 = -2.0f * acc[rt][2 * p + 1][reg];
                mn[p] = fminf(s0, s1);
            }
            #pragma unroll
            for (int sh = 1; sh < 16; sh <<= 1) {
                #pragma unroll
                for (int p = 0; p < 4; ++p)
                    mn[p] = fminf(mn[p], __shfl_xor(mn[p], sh, 64));
            }
            if (m == 0) {   // lanes 0,16,32,48 (one per quad)
                int row = n0 + 64 * w + 16 * rt + 4 * q + reg;
                #pragma unroll
                for (int p = 0; p < 4; ++p)
                    sbmin[(size_t)row * 256 + (blockIdx.y << 2) + p] = mn[p];
                float m4 = fminf(fminf(mn[0], mn[1]), fminf(mn[2], mn[3]));
                atomicMin(&rowmin[row], forder(m4));
            }
        }
    }
}

// Exact rescore (unchanged arithmetic): qualifying subblocks rescored with the
// EXACT chain (sequential k fp32 fmaf, fl32(rn-2*dot)); ties -> lowest index.
// XCD-LOCALITY SWIZZLE (round 11): row = (bid&7)*2048 + (bid>>3). The 16 rows
// sharing each 64B hs-line map to blocks with the same bid%8 (same XCD under
// the round-robin heuristic) inside a ~128-block concurrency window, so each
// line is fetched into one L2 once instead of 8 (round 10: FETCH 310 MB).
__global__ __launch_bounds__(64)
void rescore(const float* __restrict__ hs, const float* __restrict__ cb,
             const float* __restrict__ rn, const float* __restrict__ sbmin,
             const u32* __restrict__ rowmin, u64* __restrict__ keys) {
    __shared__ float fs[256];
    __shared__ int list[256];
    __shared__ int cnt;
    const int bid = blockIdx.x;
    const int row = ((bid & 7) << 11) + (bid >> 3);
    const int l = threadIdx.x;
    if (l == 0) cnt = 0;
    const int b = row >> 10, hw = row & 1023;
    const float* hp = hs + (size_t)b * CHW + hw;
    #pragma unroll
    for (int j = 0; j < 4; ++j) fs[l + 64 * j] = hp[(size_t)(l + 64 * j) * HW];
    __syncthreads();

    float thr = unforder(rowmin[row]) + TAU;
    #pragma unroll
    for (int j = 0; j < 4; ++j) {
        int sb = l + 64 * j;
        if (sbmin[(size_t)row * 256 + sb] <= thr) {
            int pos = atomicAdd(&cnt, 1);
            list[pos] = sb;
        }
    }
    __syncthreads();
    const int C = cnt;
    const float rn_row = rn[row];
    u64 best = ~0ull;
    for (int it = 0; it < C; it += 2) {
        int slot = it + (l >> 5);
        if (slot < C) {
            int code = list[slot] * 32 + (l & 31);
            const float4* e4 = reinterpret_cast<const float4*>(&cb[(size_t)code << 8]);
            float acc = 0.0f;
            #pragma unroll 16
            for (int kk = 0; kk < 64; ++kk) {
                float4 ev = e4[kk];
                float4 fv = *reinterpret_cast<const float4*>(&fs[kk << 2]);
                acc = fmaf(fv.x, ev.x, acc);
                acc = fmaf(fv.y, ev.y, acc);
                acc = fmaf(fv.z, ev.z, acc);
                acc = fmaf(fv.w, ev.w, acc);
            }
            float s = __fadd_rn(rn_row, -2.0f * acc);
            u64 key = ((u64)forder(s) << 32) | (u64)code;
            if (key < best) best = key;
        }
    }
    #pragma unroll
    for (int sh = 1; sh < 64; sh <<= 1) {
        u64 o = __shfl_xor(best, sh, 64);
        if (o < best) best = o;
    }
    if (l == 0) keys[row] = best;
}

// Gather: 512 blocks, each owns (b, 32-hw chunk) x all 256 c. cb rows read
// coalesced once into LDS; outputs coalesced. Values exact: x + (q - x).
__global__ __launch_bounds__(256)
void gather_kernel(const float* __restrict__ hs, const float* __restrict__ cb,
                   const u64* __restrict__ keys, float* __restrict__ out) {
    __shared__ int codes_s[32];
    __shared__ float q_s[32][257];
    __shared__ float red[4];
    const int g = blockIdx.x;
    const int b = g >> 5;
    const int hw0 = (g & 31) << 5;
    const int t = threadIdx.x;
    const int nbase = b * HW + hw0;

    if (t < 32) {
        int code = (int)(keys[nbase + t] & 0xFFFFFFFFULL);
        codes_s[t] = code;
        out[IDX_OFF + nbase + t] = (float)code;
    }
    __syncthreads();

    const int r = t >> 3, f4 = t & 7;
    const float4* crow = reinterpret_cast<const float4*>(cb + (size_t)codes_s[r] * DIM);
    #pragma unroll
    for (int j = 0; j < 8; ++j) {
        float4 v = crow[f4 + 8 * j];
        *reinterpret_cast<float4*>(&q_s[r][4 * (f4 + 8 * j)]) = v;
    }
    __syncthreads();

    float d2 = 0.0f;
    const int hw = t & 31, cof = t >> 5;   // 8 c-lanes
    #pragma unroll 8
    for (int it = 0; it < 32; ++it) {
        int c = it * 8 + cof;
        size_t off = (size_t)b * CHW + (size_t)c * HW + hw0 + hw;
        float x = hs[off];
        float qv = q_s[hw][c];
        out[off] = x + (qv - x);           // straight-through forward, exact formula
        float d = qv - x;
        d2 = fmaf(d, d, d2);
    }
    #pragma unroll
    for (int sh = 32; sh >= 1; sh >>= 1) d2 += __shfl_xor(d2, sh, 64);
    if ((t & 63) == 0) red[t >> 6] = d2;
    __syncthreads();
    if (t == 0) {
        float tot = red[0] + red[1] + red[2] + red[3];
        atomicAdd(out + LOSS_OFF, tot * (1.25f / 4194304.0f));  // (1+0.25)*mean
    }
}

extern "C" void kernel_launch(void* const* d_in, const int* in_sizes, int n_in,
                              void* d_out, int out_size, void* d_ws, size_t ws_size,
                              hipStream_t stream) {
    const float* hs = (const float*)d_in[0];   // (16,256,32,32) f32
    const float* cb = (const float*)d_in[1];   // (8192,256) f32
    float* out = (float*)d_out;
    char* ws = (char*)d_ws;
    u64*      keys   = (u64*)(ws + 0);
    float*    rn     = (float*)(ws + 131072);
    u32*      rowmin = (u32*)(ws + 196608);
    ushort_t* Abf    = (ushort_t*)(ws + 262144);
    ushort_t* Bbf    = (ushort_t*)(ws + 8650752);
    float*    sbmin  = (float*)(ws + 12845056);

    convert_hs<<<NROWS / 64, 64, 0, stream>>>(hs, Abf, rn, rowmin, out);
    convert_cb<<<1024, 256, 0, stream>>>(cb, Bbf);
    mfma_approx<<<dim3(NROWS / 256, KCODES / 128), 256, 0, stream>>>(Abf, Bbf, sbmin, rowmin);
    rescore<<<NROWS, 64, 0, stream>>>(hs, cb, rn, sbmin, rowmin, keys);
    gather_kernel<<<512, 256, 0, stream>>>(hs, cb, keys, out);
}